// Round 1
// baseline (334.453 us; speedup 1.0000x reference)
//
#include <hip/hip_runtime.h>
#include <hip/hip_bf16.h>

typedef _Float16 half4v __attribute__((ext_vector_type(4)));
typedef _Float16 half8v __attribute__((ext_vector_type(8)));
typedef float float4v __attribute__((ext_vector_type(4)));

#define L_SEQ 2048
#define EMB 1024
#define NH 16
#define DKV 64

// ---------------------------------------------------------------------------
// Kernel 0: pack + transpose + cast W_qkv (fp32 [1024][3072]) -> Wt (f16 [2048][1024])
// Output col n: head h = n>>7, within-head r = n&127 (r<64 -> Q col r, r>=64 -> K col r-64)
// Original W column = h*192 + r  (Q cols at h*192+0..63, K cols at h*192+64..127)
// ---------------------------------------------------------------------------
__global__ __launch_bounds__(256) void wpack_kernel(const float* __restrict__ W,
                                                    _Float16* __restrict__ Wt) {
  __shared__ float tile[32][33];
  int n0 = blockIdx.x * 32;
  int k0 = blockIdx.y * 32;
  int h = n0 >> 7;
  int wc = h * 192 + (n0 & 127);
  int tx = threadIdx.x & 31;
  int ty = threadIdx.x >> 5;  // 0..7
#pragma unroll
  for (int i = 0; i < 4; ++i) {
    int k = ty + i * 8;
    tile[k][tx] = W[(size_t)(k0 + k) * 3072 + wc + tx];
  }
  __syncthreads();
#pragma unroll
  for (int i = 0; i < 4; ++i) {
    int n = ty + i * 8;
    Wt[(size_t)(n0 + n) * 1024 + k0 + tx] = (_Float16)tile[tx][n];
  }
}

// ---------------------------------------------------------------------------
// Kernel 1: Q/K projection GEMM.  [4096 x 1024] fp32 @ Wt^T -> Q,K f16 [B][H][L][64]
// BM=BN=128, BK=32, 256 threads (4 waves, 2x2), 16x16x32 f16 MFMA, 4x4 frags/wave.
// ---------------------------------------------------------------------------
__global__ __launch_bounds__(256) void qk_gemm_kernel(const float* __restrict__ X,
                                                      const _Float16* __restrict__ Wt,
                                                      const float* __restrict__ bias,
                                                      _Float16* __restrict__ Qh,
                                                      _Float16* __restrict__ Kh) {
  __shared__ _Float16 As[128][40];  // +8 pad: 80B row stride, 16B aligned
  __shared__ _Float16 Bs[128][40];
  int n0 = blockIdx.x * 128;
  int m0 = blockIdx.y * 128;
  int t = threadIdx.x;
  int l = t & 63;
  int wv = t >> 6;
  int wm = wv >> 1, wn = wv & 1;
  int cl = l & 15, ko = (l >> 4) * 8;
  float4v acc[4][4] = {};
  for (int k0 = 0; k0 < 1024; k0 += 32) {
    // stage A: 128x32 fp32 -> f16
#pragma unroll
    for (int i = 0; i < 4; ++i) {
      int idx = t + i * 256;
      int row = idx >> 3;
      int c4 = (idx & 7) * 4;
      float4v v = *(const float4v*)(X + (size_t)(m0 + row) * 1024 + k0 + c4);
      half4v hv;
      hv[0] = (_Float16)v[0]; hv[1] = (_Float16)v[1];
      hv[2] = (_Float16)v[2]; hv[3] = (_Float16)v[3];
      *(half4v*)(&As[row][c4]) = hv;
    }
    // stage B: 128x32 f16 (already packed/transposed)
#pragma unroll
    for (int i = 0; i < 2; ++i) {
      int idx = t + i * 256;
      int row = idx >> 2;
      int c8 = (idx & 3) * 8;
      *(half8v*)(&Bs[row][c8]) = *(const half8v*)(Wt + (size_t)(n0 + row) * 1024 + k0 + c8);
    }
    __syncthreads();
    half8v a[4], b[4];
#pragma unroll
    for (int mt = 0; mt < 4; ++mt) a[mt] = *(const half8v*)(&As[wm * 64 + mt * 16 + cl][ko]);
#pragma unroll
    for (int nt = 0; nt < 4; ++nt) b[nt] = *(const half8v*)(&Bs[wn * 64 + nt * 16 + cl][ko]);
#pragma unroll
    for (int mt = 0; mt < 4; ++mt)
#pragma unroll
      for (int nt = 0; nt < 4; ++nt)
        acc[mt][nt] = __builtin_amdgcn_mfma_f32_16x16x32_f16(a[mt], b[nt], acc[mt][nt], 0, 0, 0);
    __syncthreads();
  }
  // epilogue: bias + cast + scatter to Q/K [B][H][L][64]
#pragma unroll
  for (int mt = 0; mt < 4; ++mt) {
#pragma unroll
    for (int nt = 0; nt < 4; ++nt) {
      int n_g = n0 + wn * 64 + nt * 16 + cl;
      int hh = n_g >> 7, rr = n_g & 127;
      float bv = bias[hh * 192 + rr];
      _Float16* dstbase = (rr < 64) ? Qh : Kh;
      int d = rr & 63;
#pragma unroll
      for (int r = 0; r < 4; ++r) {
        int row_g = m0 + wm * 64 + mt * 16 + (l >> 4) * 4 + r;
        int bb = row_g >> 11, lr = row_g & 2047;
        dstbase[(((size_t)bb * NH + hh) * L_SEQ + lr) * DKV + d] = (_Float16)(acc[mt][nt][r] + bv);
      }
    }
  }
}

// ---------------------------------------------------------------------------
// Kernel 2: S = Q K^T / 8, softmax over cols, write [B][H][L][L] fp32.
// Block = (b, h, 64-row slab); 4 waves x 16 rows. Two passes (sum, then write);
// no max-subtraction needed (|s| <~ 15, exp fits fp32 easily; matches jax in fp32).
// ---------------------------------------------------------------------------
__global__ __launch_bounds__(256) void attn_softmax_kernel(const _Float16* __restrict__ Qh,
                                                           const _Float16* __restrict__ Kh,
                                                           float* __restrict__ out) {
  int rb = blockIdx.x;
  int bh = blockIdx.z * NH + blockIdx.y;
  int t = threadIdx.x;
  int l = t & 63;
  int wv = t >> 6;
  int cl = l & 15, ko = (l >> 4) * 8;
  const _Float16* Qb = Qh + ((size_t)bh * L_SEQ + rb * 64 + wv * 16) * DKV;
  const _Float16* Kb = Kh + (size_t)bh * L_SEQ * DKV;
  half8v aq0 = *(const half8v*)(Qb + (size_t)cl * DKV + ko);
  half8v aq1 = *(const half8v*)(Qb + (size_t)cl * DKV + 32 + ko);
  const float SC = 0.18033688011112042f;  // log2(e)/sqrt(64)

  float sum[4] = {0.f, 0.f, 0.f, 0.f};
  for (int j0 = 0; j0 < L_SEQ; j0 += 16) {
    const _Float16* Kp = Kb + (size_t)(j0 + cl) * DKV;
    half8v b0 = *(const half8v*)(Kp + ko);
    half8v b1 = *(const half8v*)(Kp + 32 + ko);
    float4v acc = {0.f, 0.f, 0.f, 0.f};
    acc = __builtin_amdgcn_mfma_f32_16x16x32_f16(aq0, b0, acc, 0, 0, 0);
    acc = __builtin_amdgcn_mfma_f32_16x16x32_f16(aq1, b1, acc, 0, 0, 0);
#pragma unroll
    for (int r = 0; r < 4; ++r) sum[r] += __builtin_amdgcn_exp2f(acc[r] * SC);
  }
#pragma unroll
  for (int r = 0; r < 4; ++r) {
    sum[r] += __shfl_xor(sum[r], 1);
    sum[r] += __shfl_xor(sum[r], 2);
    sum[r] += __shfl_xor(sum[r], 4);
    sum[r] += __shfl_xor(sum[r], 8);
  }
  float inv[4];
#pragma unroll
  for (int r = 0; r < 4; ++r) inv[r] = 1.0f / sum[r];

  size_t obase = ((size_t)bh * L_SEQ + rb * 64 + wv * 16 + (l >> 4) * 4) * L_SEQ;
  for (int j0 = 0; j0 < L_SEQ; j0 += 16) {
    const _Float16* Kp = Kb + (size_t)(j0 + cl) * DKV;
    half8v b0 = *(const half8v*)(Kp + ko);
    half8v b1 = *(const half8v*)(Kp + 32 + ko);
    float4v acc = {0.f, 0.f, 0.f, 0.f};
    acc = __builtin_amdgcn_mfma_f32_16x16x32_f16(aq0, b0, acc, 0, 0, 0);
    acc = __builtin_amdgcn_mfma_f32_16x16x32_f16(aq1, b1, acc, 0, 0, 0);
#pragma unroll
    for (int r = 0; r < 4; ++r)
      out[obase + (size_t)r * L_SEQ + j0 + cl] = __builtin_amdgcn_exp2f(acc[r] * SC) * inv[r];
  }
}

// ---------------------------------------------------------------------------
extern "C" void kernel_launch(void* const* d_in, const int* in_sizes, int n_in,
                              void* d_out, int out_size, void* d_ws, size_t ws_size,
                              hipStream_t stream) {
  const float* X = (const float*)d_in[0];
  const float* W = (const float*)d_in[1];
  const float* bias = (const float*)d_in[2];
  float* out = (float*)d_out;
  char* ws = (char*)d_ws;
  _Float16* Wt = (_Float16*)ws;                         // 2048*1024*2 = 4 MB
  _Float16* Qh = (_Float16*)(ws + (4ull << 20));        // 2*16*2048*64*2 = 8 MB
  _Float16* Kh = (_Float16*)(ws + (12ull << 20));       // 8 MB  (total 20 MB)

  wpack_kernel<<<dim3(64, 32), 256, 0, stream>>>(W, Wt);
  qk_gemm_kernel<<<dim3(16, 32), 256, 0, stream>>>(X, Wt, bias, Qh, Kh);
  attn_softmax_kernel<<<dim3(32, NH, 2), 256, 0, stream>>>(Qh, Kh, out);
}

// Round 2
// 332.833 us; speedup vs baseline: 1.0049x; 1.0049x over previous
//
#include <hip/hip_runtime.h>
#include <hip/hip_bf16.h>

typedef _Float16 half4v __attribute__((ext_vector_type(4)));
typedef _Float16 half8v __attribute__((ext_vector_type(8)));
typedef float float4v __attribute__((ext_vector_type(4)));

#define L_SEQ 2048
#define EMB 1024
#define NH 16
#define DKV 64

__device__ inline void gll16(const void* g, void* l) {
  __builtin_amdgcn_global_load_lds((const __attribute__((address_space(1))) void*)g,
                                   (__attribute__((address_space(3))) void*)l, 16, 0, 0);
}

// ---------------------------------------------------------------------------
// Kernel A: cast X fp32 -> f16 (4096x1024), 8 elems/thread
// ---------------------------------------------------------------------------
__global__ __launch_bounds__(256) void xcast_kernel(const float* __restrict__ X,
                                                    _Float16* __restrict__ X16) {
  size_t i = ((size_t)blockIdx.x * 256 + threadIdx.x) * 8;
  float4v v0 = *(const float4v*)(X + i);
  float4v v1 = *(const float4v*)(X + i + 4);
  half8v h;
  h[0] = (_Float16)v0[0]; h[1] = (_Float16)v0[1]; h[2] = (_Float16)v0[2]; h[3] = (_Float16)v0[3];
  h[4] = (_Float16)v1[0]; h[5] = (_Float16)v1[1]; h[6] = (_Float16)v1[2]; h[7] = (_Float16)v1[3];
  *(half8v*)(X16 + i) = h;
}

// ---------------------------------------------------------------------------
// Kernel B: pack + transpose + cast W_qkv (fp32 [1024][3072]) -> Wt (f16 [2048][1024])
// ---------------------------------------------------------------------------
__global__ __launch_bounds__(256) void wpack_kernel(const float* __restrict__ W,
                                                    _Float16* __restrict__ Wt) {
  __shared__ float tile[32][33];
  int n0 = blockIdx.x * 32;
  int k0 = blockIdx.y * 32;
  int h = n0 >> 7;
  int wc = h * 192 + (n0 & 127);
  int tx = threadIdx.x & 31;
  int ty = threadIdx.x >> 5;
#pragma unroll
  for (int i = 0; i < 4; ++i) {
    int k = ty + i * 8;
    tile[k][tx] = W[(size_t)(k0 + k) * 3072 + wc + tx];
  }
  __syncthreads();
#pragma unroll
  for (int i = 0; i < 4; ++i) {
    int n = ty + i * 8;
    Wt[(size_t)(n0 + n) * 1024 + k0 + tx] = (_Float16)tile[tx][n];
  }
}

// ---------------------------------------------------------------------------
// Kernel C: Q/K projection GEMM (m97 structure: global_load_lds 16B, linear LDS)
// X16 f16 [4096][1024] @ Wt^T -> Q,K f16 [B][H][L][64]
// BM=BN=128, BK=32, 256 threads (4 waves 2x2), 16x16x32 f16 MFMA, 4x4 frags/wave
// ---------------------------------------------------------------------------
__global__ __launch_bounds__(256) void qk_gemm_kernel(const _Float16* __restrict__ X16,
                                                      const _Float16* __restrict__ Wt,
                                                      const float* __restrict__ bias,
                                                      _Float16* __restrict__ Qh,
                                                      _Float16* __restrict__ Kh) {
  __shared__ _Float16 As[128 * 32];
  __shared__ _Float16 Bs[128 * 32];
  int n0 = blockIdx.x * 128;
  int m0 = blockIdx.y * 128;
  int t = threadIdx.x;
  int l = t & 63;
  int wv = t >> 6;
  int wm = wv >> 1, wn = wv & 1;
  int cl = l & 15, ko = (l >> 4) * 8;
  int srow = (l >> 2);          // 0..15 within a 16-row chunk
  int scol = (l & 3) * 8;       // f16 col offset
  float4v acc[4][4] = {};
  for (int k0 = 0; k0 < 1024; k0 += 32) {
#pragma unroll
    for (int c = 0; c < 2; ++c) {
      int rbase = wv * 32 + c * 16;
      gll16(X16 + (size_t)(m0 + rbase + srow) * 1024 + k0 + scol, &As[rbase * 32]);
      gll16(Wt + (size_t)(n0 + rbase + srow) * 1024 + k0 + scol, &Bs[rbase * 32]);
    }
    __syncthreads();
    half8v a[4], b[4];
#pragma unroll
    for (int mt = 0; mt < 4; ++mt) a[mt] = *(const half8v*)(&As[(wm * 64 + mt * 16 + cl) * 32 + ko]);
#pragma unroll
    for (int nt = 0; nt < 4; ++nt) b[nt] = *(const half8v*)(&Bs[(wn * 64 + nt * 16 + cl) * 32 + ko]);
#pragma unroll
    for (int mt = 0; mt < 4; ++mt)
#pragma unroll
      for (int nt = 0; nt < 4; ++nt)
        acc[mt][nt] = __builtin_amdgcn_mfma_f32_16x16x32_f16(a[mt], b[nt], acc[mt][nt], 0, 0, 0);
    __syncthreads();
  }
#pragma unroll
  for (int mt = 0; mt < 4; ++mt) {
#pragma unroll
    for (int nt = 0; nt < 4; ++nt) {
      int n_g = n0 + wn * 64 + nt * 16 + cl;
      int hh = n_g >> 7, rr = n_g & 127;
      float bv = bias[hh * 192 + rr];
      _Float16* dstbase = (rr < 64) ? Qh : Kh;
      int d = rr & 63;
#pragma unroll
      for (int r = 0; r < 4; ++r) {
        int row_g = m0 + wm * 64 + mt * 16 + (l >> 4) * 4 + r;
        int bb = row_g >> 11, lr = row_g & 2047;
        dstbase[(((size_t)bb * NH + hh) * L_SEQ + lr) * DKV + d] = (_Float16)(acc[mt][nt][r] + bv);
      }
    }
  }
}

// ---------------------------------------------------------------------------
// Kernel D: S = Q K^T / 8, softmax over j, write [B][H][L][L] fp32.
// Swapped-operand MFMA: D rows = j (K index), D cols = q  -> float4 stores.
// Block = 64 q-rows of one (b,h); 4 waves x 16 rows. XCD swizzle: all 32
// rb-slabs of one (b,h) land on the same XCD (K panel L2-resident).
// ---------------------------------------------------------------------------
__global__ __launch_bounds__(256) void attn_softmax_kernel(const _Float16* __restrict__ Qh,
                                                           const _Float16* __restrict__ Kh,
                                                           float* __restrict__ out) {
  int id = blockIdx.x;
  int xcd = id & 7;
  int rest = id >> 3;
  int rb = rest & 31;
  int bh = ((rest >> 5) << 3) + xcd;   // bijective: id = (bh&7) + 8*(rb + 32*(bh>>3))
  int t = threadIdx.x;
  int l = t & 63;
  int wv = t >> 6;
  int cl = l & 15, ko = (l >> 4) * 8;
  int q0 = rb * 64 + wv * 16;
  const _Float16* Qb = Qh + ((size_t)bh * L_SEQ + q0) * DKV;
  const _Float16* Kb = Kh + (size_t)bh * L_SEQ * DKV;
  half8v aq0 = *(const half8v*)(Qb + cl * DKV + ko);
  half8v aq1 = *(const half8v*)(Qb + cl * DKV + 32 + ko);
  const float SC = 0.18033688011112042f;  // log2(e)/sqrt(64)

  // Pass 1: row sums
  float lsum = 0.f;
#pragma unroll 4
  for (int j0 = 0; j0 < L_SEQ; j0 += 16) {
    const _Float16* Kp = Kb + (size_t)(j0 + cl) * DKV;
    half8v b0 = *(const half8v*)(Kp + ko);
    half8v b1 = *(const half8v*)(Kp + 32 + ko);
    float4v acc = {};
    acc = __builtin_amdgcn_mfma_f32_16x16x32_f16(b0, aq0, acc, 0, 0, 0);
    acc = __builtin_amdgcn_mfma_f32_16x16x32_f16(b1, aq1, acc, 0, 0, 0);
    lsum += __builtin_amdgcn_exp2f(acc[0] * SC) + __builtin_amdgcn_exp2f(acc[1] * SC) +
            __builtin_amdgcn_exp2f(acc[2] * SC) + __builtin_amdgcn_exp2f(acc[3] * SC);
  }
  // reduce across the 4 lanes sharing cl (lanes l, l^16, l^32, l^48)
  lsum += __shfl_xor(lsum, 16);
  lsum += __shfl_xor(lsum, 32);
  float inv = 1.0f / lsum;

  // Pass 2: recompute, normalize, float4 stores (lane = one q-row, 4 consecutive j)
  size_t ob = ((size_t)bh * L_SEQ + q0 + cl) * L_SEQ + (l >> 4) * 4;
#pragma unroll 4
  for (int j0 = 0; j0 < L_SEQ; j0 += 16) {
    const _Float16* Kp = Kb + (size_t)(j0 + cl) * DKV;
    half8v b0 = *(const half8v*)(Kp + ko);
    half8v b1 = *(const half8v*)(Kp + 32 + ko);
    float4v acc = {};
    acc = __builtin_amdgcn_mfma_f32_16x16x32_f16(b0, aq0, acc, 0, 0, 0);
    acc = __builtin_amdgcn_mfma_f32_16x16x32_f16(b1, aq1, acc, 0, 0, 0);
    float4v p;
    p[0] = __builtin_amdgcn_exp2f(acc[0] * SC) * inv;
    p[1] = __builtin_amdgcn_exp2f(acc[1] * SC) * inv;
    p[2] = __builtin_amdgcn_exp2f(acc[2] * SC) * inv;
    p[3] = __builtin_amdgcn_exp2f(acc[3] * SC) * inv;
    *(float4v*)(out + ob + j0) = p;
  }
}

// ---------------------------------------------------------------------------
extern "C" void kernel_launch(void* const* d_in, const int* in_sizes, int n_in,
                              void* d_out, int out_size, void* d_ws, size_t ws_size,
                              hipStream_t stream) {
  const float* X = (const float*)d_in[0];
  const float* W = (const float*)d_in[1];
  const float* bias = (const float*)d_in[2];
  float* out = (float*)d_out;
  char* ws = (char*)d_ws;
  _Float16* Wt = (_Float16*)ws;                       // 4 MB
  _Float16* Qh = (_Float16*)(ws + (4ull << 20));      // 8 MB
  _Float16* Kh = (_Float16*)(ws + (12ull << 20));     // 8 MB
  _Float16* X16 = (_Float16*)(ws + (20ull << 20));    // 8 MB (total 28 MB)

  xcast_kernel<<<2048, 256, 0, stream>>>(X, X16);
  wpack_kernel<<<dim3(64, 32), 256, 0, stream>>>(W, Wt);
  qk_gemm_kernel<<<dim3(16, 32), 256, 0, stream>>>(X16, Wt, bias, Qh, Kh);
  attn_softmax_kernel<<<1024, 256, 0, stream>>>(Qh, Kh, out);
}